// Round 7
// baseline (2125.884 us; speedup 1.0000x reference)
//
#include <hip/hip_runtime.h>
#include <math.h>

// VQ-VAE quantizer: N=16384 pixels, D=256, K=8192 codes.
// d_out (float32) layout: [0]=loss, [1..4194304]=z_q_x (B,C,H,W),
// [4194305]=perplexity, [4194306..+16384]=idx (as float).
//
// np-exact semantics (verified r3/r4/r6): dist = f32(f32(sx2+se2)-f32(2*acc)),
// acc = sequential d=0..255 fp32 FMA chain; np.argmin first-min tie-break.
// r7: 8 waves (2/SIMD) + BARRIER-FREE main loop (per-wave E staging: each
// wave stages exactly the code-slice it reads -> in-wave lgkmcnt ordering
// replaces __syncthreads). X persistent LDS; E dbuf staggered conflict-free.

#define K_EMB 8192
#define D_EMB 256
#define NPIX  16384
#define NDTOT 4194304   // NPIX * D_EMB

#define OUT_LOSS 0
#define OUT_ZQ   1
#define OUT_PERP 4194305
#define OUT_IDX  4194306

// ws layout (bytes): [0] float sse; [256] int hist[8192];
// [33024] float se2[8192]; [65792] float sx2[16384]
#define WS_HIST_OFF 256
#define WS_SE2_OFF  (256 + 32768)
#define WS_SX2_OFF  (256 + 32768 + 32768)

// argmin geometry: 512 thr = 8 waves; wave w owns codes [128w,128w+128) of a
// 1024-code k-tile; lane = 8*ml + nl -> 8px x 16codes register tile.
#define TN 64                  // pixels per block (grid = 256)
#define TKT 1024               // codes per k-tile (8 waves x 128)
#define DC 8                   // d per step
#define NSTEP 256              // 8 kt x 32 dc
#define XSTRIDE 68             // X [256][68] floats
#define XWORDS (256 * XSTRIDE) // 17408
#define EROW 1284              // staggered row: ca = 160w + u + 4*(u>>4)
#define EBUF (DC * EROW)       // 10272 floats per buffer
#define SMEM_WORDS (XWORDS + 2 * EBUF)
#define SMEM_BYTES (SMEM_WORDS * 4)   // 151808 B

// ---------------------------------------------------------------------------
// sx2[n] = numpy-pairwise sum of x[n][d]^2 (two 128-blocks, 8 accumulators).
__global__ void sx2_kernel(const float* __restrict__ z,
                           float* __restrict__ sx2) {
#pragma clang fp contract(off)
    int n = blockIdx.x * 256 + threadIdx.x;
    int b = n >> 10, hw = n & 1023;
    const float* zb = z + (size_t)b * (D_EMB * 1024) + hw;
    float half[2];
#pragma unroll
    for (int h = 0; h < 2; ++h) {
        float r[8];
#pragma unroll
        for (int j = 0; j < 8; ++j) {
            float v = zb[(size_t)(h * 128 + j) * 1024];
            r[j] = v * v;
        }
        for (int i = 8; i < 128; i += 8)
#pragma unroll
            for (int j = 0; j < 8; ++j) {
                float v = zb[(size_t)(h * 128 + i + j) * 1024];
                float sq = v * v;
                r[j] = r[j] + sq;
            }
        half[h] = ((r[0] + r[1]) + (r[2] + r[3]))
                + ((r[4] + r[5]) + (r[6] + r[7]));
    }
    sx2[n] = half[0] + half[1];
}

// ---------------------------------------------------------------------------
// se2[k] = numpy-pairwise sum of emb[k][d]^2.
__global__ void se2_kernel(const float* __restrict__ emb,
                           float* __restrict__ se2) {
#pragma clang fp contract(off)
    int k = blockIdx.x * 256 + threadIdx.x;
    const float* e = emb + (size_t)k * D_EMB;
    float half[2];
#pragma unroll
    for (int h = 0; h < 2; ++h) {
        float r[8];
#pragma unroll
        for (int j = 0; j < 8; ++j) {
            float v = e[h * 128 + j];
            r[j] = v * v;
        }
        for (int i = 8; i < 128; i += 8)
#pragma unroll
            for (int j = 0; j < 8; ++j) {
                float v = e[h * 128 + i + j];
                float sq = v * v;
                r[j] = r[j] + sq;
            }
        half[h] = ((r[0] + r[1]) + (r[2] + r[3]))
                + ((r[4] + r[5]) + (r[6] + r[7]));
    }
    se2[k] = half[0] + half[1];
}

// ---------------------------------------------------------------------------
// Fused distance GEMM + argmin. 512 thr = 8 waves, 2 waves/SIMD.
// Wave w reads/writes ONLY E cols [160w, 160w+156) -> no barriers in loop.
__global__ __launch_bounds__(512, 2) void argmin_kernel(
        const float* __restrict__ z, const float* __restrict__ emb,
        const float* __restrict__ se2, const float* __restrict__ sx2,
        float* __restrict__ out_idx) {
#pragma clang fp contract(off)
    extern __shared__ float smem[];
    float* Xs    = smem;               // [256][XSTRIDE]
    float* Ebase = smem + XWORDS;      // [2][DC][EROW]

    const int t    = threadIdx.x;
    const int lane = t & 63;
    const int w    = t >> 6;           // 0..7
    const int nl   = lane & 7;
    const int ml   = lane >> 3;
    const int n0   = blockIdx.x * TN;
    const int b    = n0 >> 10;         // HW = 1024
    const int hw0  = n0 & 1023;
    const float* zb = z + (size_t)b * (D_EMB * 1024) + hw0;

    // ---- stage X (64 px x 256 d) once: 8 float4 per thread ----
    {
        int px4 = t & 15;
        int dr  = t >> 4;              // 0..31
#pragma unroll
        for (int r = 0; r < 8; ++r) {
            int d = 32 * r + dr;
            float4 v = *(const float4*)(zb + (size_t)d * 1024 + 4 * px4);
            *(float4*)&Xs[d * XSTRIDE + 4 * px4] = v;
        }
    }

    // E staging (wave-local): lane = 2*su + sh; code u = su + 32p, p in [0,4);
    // d-half sh -> global float4 at d = dc*8 + 4*sh; write col
    // ca = 160w + u + 4*(u>>4), rows 4*sh+j.  Write banks <=2-way (free).
    const int su = lane >> 1;
    const int sh = lane & 1;
    const float* embw = emb + (size_t)(128 * w) * 256;   // wave's code slice

    // prologue: stage tile 0 (kt=0, dc=0) into buffer 0 (wave-local)
    {
        float4 v[4];
#pragma unroll
        for (int p = 0; p < 4; ++p) {
            int u = su + 32 * p;
            v[p] = *(const float4*)(embw + (size_t)u * 256 + 4 * sh);
        }
#pragma unroll
        for (int p = 0; p < 4; ++p) {
            int u  = su + 32 * p;
            int ca = 160 * w + u + 4 * (u >> 4);
            float* dst = Ebase + (4 * sh) * EROW + ca;
            dst[0 * EROW] = v[p].x;
            dst[1 * EROW] = v[p].y;
            dst[2 * EROW] = v[p].z;
            dst[3 * EROW] = v[p].w;
        }
    }
    __syncthreads();   // X visible to all waves (E is wave-local anyway)

    float sx2r[8];
#pragma unroll
    for (int i = 0; i < 8; ++i)
        sx2r[i] = sx2[n0 + 8 * ml + i];

    float minv[8];
    int   mini[8];
    float acc[8][16];
#pragma unroll
    for (int i = 0; i < 8; ++i) {
        minv[i] = 3.0e38f; mini[i] = 0;
#pragma unroll
        for (int ce = 0; ce < 16; ++ce) acc[i][ce] = 0.0f;
    }

    // E read base: col = 160w + 20nl (+0..15); conflict-free (32 banks, bcast)
    const int erd = 160 * w + 20 * nl;

    for (int s = 0; s < NSTEP; ++s) {
        const bool pf = (s + 1 < NSTEP);

        // T14: issue next tile's global loads early (hide under compute)
        float4 v[4];
        if (pf) {
            const int kt1 = (s + 1) >> 5, dc1 = (s + 1) & 31;
            const float* src = embw + (size_t)kt1 * TKT * 256 + dc1 * 8 + 4 * sh;
#pragma unroll
            for (int p = 0; p < 4; ++p)
                v[p] = *(const float4*)(src + (size_t)(su + 32 * p) * 256);
        }

        // compute: DC=8 d, 128 FMA each; global d = (s&31)*8 + d ascending
        const float* Ec  = Ebase + (s & 1) * EBUF;
        const int    dg0 = (s & 31) * 8;
#pragma unroll
        for (int d = 0; d < DC; ++d) {
            const float* xr = &Xs[(dg0 + d) * XSTRIDE + 8 * ml];
            float4 xa = *(const float4*)(xr + 0);
            float4 xb = *(const float4*)(xr + 4);
            const float* er = &Ec[d * EROW + erd];
            float4 e0 = *(const float4*)(er + 0);
            float4 e1 = *(const float4*)(er + 4);
            float4 e2 = *(const float4*)(er + 8);
            float4 e3 = *(const float4*)(er + 12);
            float xv[8]  = {xa.x, xa.y, xa.z, xa.w, xb.x, xb.y, xb.z, xb.w};
            float ev[16] = {e0.x, e0.y, e0.z, e0.w, e1.x, e1.y, e1.z, e1.w,
                            e2.x, e2.y, e2.z, e2.w, e3.x, e3.y, e3.z, e3.w};
#pragma unroll
            for (int i = 0; i < 8; ++i)
#pragma unroll
                for (int ce = 0; ce < 16; ++ce)
                    acc[i][ce] = __builtin_fmaf(xv[i], ev[ce], acc[i][ce]);
        }

        // end of k-tile: dist + argmin update (k ascending), reset acc
        if ((s & 31) == 31) {
            const int kt = s >> 5;
            const int kb = kt * TKT + 128 * w + 16 * nl;
            const float* sp = &se2[kb];
            float4 s0 = *(const float4*)(sp + 0);
            float4 s1 = *(const float4*)(sp + 4);
            float4 s2 = *(const float4*)(sp + 8);
            float4 s3 = *(const float4*)(sp + 12);
            float se2v[16] = {s0.x, s0.y, s0.z, s0.w, s1.x, s1.y, s1.z, s1.w,
                              s2.x, s2.y, s2.z, s2.w, s3.x, s3.y, s3.z, s3.w};
#pragma unroll
            for (int i = 0; i < 8; ++i)
#pragma unroll
                for (int ce = 0; ce < 16; ++ce) {
                    float A = sx2r[i] + se2v[ce];
                    float dist = A - 2.0f * acc[i][ce];
                    if (dist < minv[i]) {
                        minv[i] = dist;
                        mini[i] = kb + ce;
                    }
                    acc[i][ce] = 0.0f;
                }
        }

        // write prefetched tile into the other buffer (wave-local: no barrier;
        // in-wave lgkmcnt ordering guarantees visibility at step s+1)
        if (pf) {
            float* En = Ebase + ((s + 1) & 1) * EBUF;
#pragma unroll
            for (int p = 0; p < 4; ++p) {
                int u  = su + 32 * p;
                int ca = 160 * w + u + 4 * (u >> 4);
                float* dst = En + (4 * sh) * EROW + ca;
                dst[0 * EROW] = v[p].x;
                dst[1 * EROW] = v[p].y;
                dst[2 * EROW] = v[p].z;
                dst[3 * EROW] = v[p].w;
            }
        }
    }

    // merge over the 8 nl lanes (codes) -> per-px (v,k), lexicographic
#pragma unroll
    for (int i = 0; i < 8; ++i) {
        float vv = minv[i];
        int   ki = mini[i];
#pragma unroll
        for (int m = 1; m <= 4; m <<= 1) {
            float ov = __shfl_xor(vv, m, 64);
            int   oi = __shfl_xor(ki, m, 64);
            if (ov < vv || (ov == vv && oi < ki)) { vv = ov; ki = oi; }
        }
        minv[i] = vv; mini[i] = ki;
    }

    // cross-wave merge via LDS (smem reuse -> barrier first)
    __syncthreads();
    float* Vred = smem;                 // [8][64]
    int*   Kred = (int*)(smem + 512);   // [8][64]
    if (nl == 0) {
#pragma unroll
        for (int i = 0; i < 8; ++i) {
            int pl = 8 * ml + i;
            Vred[w * 64 + pl] = minv[i];
            Kred[w * 64 + pl] = mini[i];
        }
    }
    __syncthreads();
    if (t < 64) {
        float vv = Vred[t];
        int   ki = Kred[t];
#pragma unroll
        for (int ww = 1; ww < 8; ++ww) {
            float ov = Vred[ww * 64 + t];
            int   oi = Kred[ww * 64 + t];
            if (ov < vv || (ov == vv && oi < ki)) { vv = ov; ki = oi; }
        }
        out_idx[n0 + t] = (float)ki;
    }
}

// ---------------------------------------------------------------------------
// Histogram of final indices, for perplexity.
__global__ void hist_kernel(const float* __restrict__ idxf,
                            int* __restrict__ hist) {
    int n = blockIdx.x * 256 + threadIdx.x;
    atomicAdd(&hist[(int)idxf[n]], 1);
}

// ---------------------------------------------------------------------------
// Gather quantized vectors, write z_q_x, accumulate sum of squared errors.
__global__ void quantize_kernel(const float* __restrict__ z,
                                const float* __restrict__ emb,
                                const float* __restrict__ idxf,
                                float* __restrict__ zq,
                                float* __restrict__ sse) {
    int o = (blockIdx.x * 256 + threadIdx.x) * 4;
    int hw = o & 1023;
    int c  = (o >> 10) & 255;
    int b  = o >> 18;
    int nbase = b * 1024 + hw;
    float4 x = *(const float4*)(z + o);
    float q0 = emb[(size_t)((int)idxf[nbase + 0]) * D_EMB + c];
    float q1 = emb[(size_t)((int)idxf[nbase + 1]) * D_EMB + c];
    float q2 = emb[(size_t)((int)idxf[nbase + 2]) * D_EMB + c];
    float q3 = emb[(size_t)((int)idxf[nbase + 3]) * D_EMB + c];
    float4 q = make_float4(q0, q1, q2, q3);
    *(float4*)(zq + o) = q;
    float d0 = q.x - x.x, d1 = q.y - x.y, d2 = q.z - x.z, d3 = q.w - x.w;
    float s = d0 * d0 + d1 * d1 + d2 * d2 + d3 * d3;
#pragma unroll
    for (int m = 1; m < 64; m <<= 1) s += __shfl_xor(s, m, 64);
    __shared__ float red[4];
    int lane = threadIdx.x & 63, wv = threadIdx.x >> 6;
    if (lane == 0) red[wv] = s;
    __syncthreads();
    if (threadIdx.x == 0)
        atomicAdd(sse, red[0] + red[1] + red[2] + red[3]);
}

// ---------------------------------------------------------------------------
__global__ void finalize_kernel(const int* __restrict__ hist,
                                const float* __restrict__ sse,
                                float* __restrict__ out) {
    float s = 0.0f;
    for (int i = threadIdx.x; i < K_EMB; i += 256) {
        float p = (float)hist[i] * (1.0f / (float)NPIX);
        s += p * logf(p + 1e-10f);
    }
#pragma unroll
    for (int m = 1; m < 64; m <<= 1) s += __shfl_xor(s, m, 64);
    __shared__ float red[4];
    int lane = threadIdx.x & 63, wv = threadIdx.x >> 6;
    if (lane == 0) red[wv] = s;
    __syncthreads();
    if (threadIdx.x == 0) {
        float H = -(red[0] + red[1] + red[2] + red[3]);
        out[OUT_PERP] = expf(H);
        out[OUT_LOSS] = 1.25f * sse[0] / (float)NDTOT;
    }
}

// ---------------------------------------------------------------------------
extern "C" void kernel_launch(void* const* d_in, const int* in_sizes, int n_in,
                              void* d_out, int out_size, void* d_ws, size_t ws_size,
                              hipStream_t stream) {
    const float* z   = (const float*)d_in[0];   // [16,256,32,32]
    const float* emb = (const float*)d_in[1];   // [8192,256]
    float* out = (float*)d_out;
    char*  ws  = (char*)d_ws;
    float* sse  = (float*)(ws);
    int*   hist = (int*)(ws + WS_HIST_OFF);
    float* se2  = (float*)(ws + WS_SE2_OFF);
    float* sx2  = (float*)(ws + WS_SX2_OFF);

    // allow >64KB dynamic LDS (idempotent; capture-safe host call)
    static int attr_done = 0;
    if (!attr_done) {
        (void)hipFuncSetAttribute((const void*)argmin_kernel,
                                  hipFuncAttributeMaxDynamicSharedMemorySize,
                                  SMEM_BYTES);
        attr_done = 1;
    }

    // zero sse + hist every call (graph replays don't re-poison)
    hipMemsetAsync(d_ws, 0, WS_SE2_OFF, stream);

    sx2_kernel<<<NPIX / 256, 256, 0, stream>>>(z, sx2);
    se2_kernel<<<K_EMB / 256, 256, 0, stream>>>(emb, se2);
    argmin_kernel<<<NPIX / TN, 512, SMEM_BYTES, stream>>>(z, emb, se2, sx2,
                                                          out + OUT_IDX);
    hist_kernel<<<NPIX / 256, 256, 0, stream>>>(out + OUT_IDX, hist);
    quantize_kernel<<<NDTOT / (256 * 4), 256, 0, stream>>>(
        z, emb, out + OUT_IDX, out + OUT_ZQ, sse);
    finalize_kernel<<<1, 256, 0, stream>>>(hist, sse, out);
}

// Round 8
// 2111.665 us; speedup vs baseline: 1.0067x; 1.0067x over previous
//
#include <hip/hip_runtime.h>
#include <math.h>

// VQ-VAE quantizer: N=16384 pixels, D=256, K=8192 codes.
// d_out (float32) layout: [0]=loss, [1..4194304]=z_q_x (B,C,H,W),
// [4194305]=perplexity, [4194306..+16384]=idx (as float).
//
// np-exact semantics (verified r3/r4/r6/r7): dist = f32(f32(sx2+se2)-f32(2*acc)),
// acc = sequential d=0..255 fp32 FMA chain; np.argmin first-min tie-break.
// r8: r7 structure (8 waves, barrier-free wave-local E dbuf) with the spill
// fixed: __launch_bounds__(512,1) -> VGPR cap 256 (r7's (512,2) capped at 128
// and spilled acc[8][16] -> 5.9 GB scratch writes/dispatch).

#define K_EMB 8192
#define D_EMB 256
#define NPIX  16384
#define NDTOT 4194304   // NPIX * D_EMB

#define OUT_LOSS 0
#define OUT_ZQ   1
#define OUT_PERP 4194305
#define OUT_IDX  4194306

// ws layout (bytes): [0] float sse; [256] int hist[8192];
// [33024] float se2[8192]; [65792] float sx2[16384]
#define WS_HIST_OFF 256
#define WS_SE2_OFF  (256 + 32768)
#define WS_SX2_OFF  (256 + 32768 + 32768)

// argmin geometry: 512 thr = 8 waves; wave w owns codes [128w,128w+128) of a
// 1024-code k-tile; lane = 8*ml + nl -> 8px x 16codes register tile.
#define TN 64                  // pixels per block (grid = 256)
#define TKT 1024               // codes per k-tile (8 waves x 128)
#define DC 8                   // d per step
#define NSTEP 256              // 8 kt x 32 dc
#define XSTRIDE 68             // X [256][68] floats
#define XWORDS (256 * XSTRIDE) // 17408
#define EROW 1284              // staggered row: ca = 160w + u + 4*(u>>4)
#define EBUF (DC * EROW)       // 10272 floats per buffer
#define SMEM_WORDS (XWORDS + 2 * EBUF)
#define SMEM_BYTES (SMEM_WORDS * 4)   // 151808 B

// ---------------------------------------------------------------------------
// sx2[n] = numpy-pairwise sum of x[n][d]^2 (two 128-blocks, 8 accumulators).
__global__ void sx2_kernel(const float* __restrict__ z,
                           float* __restrict__ sx2) {
#pragma clang fp contract(off)
    int n = blockIdx.x * 256 + threadIdx.x;
    int b = n >> 10, hw = n & 1023;
    const float* zb = z + (size_t)b * (D_EMB * 1024) + hw;
    float half[2];
#pragma unroll
    for (int h = 0; h < 2; ++h) {
        float r[8];
#pragma unroll
        for (int j = 0; j < 8; ++j) {
            float v = zb[(size_t)(h * 128 + j) * 1024];
            r[j] = v * v;
        }
        for (int i = 8; i < 128; i += 8)
#pragma unroll
            for (int j = 0; j < 8; ++j) {
                float v = zb[(size_t)(h * 128 + i + j) * 1024];
                float sq = v * v;
                r[j] = r[j] + sq;
            }
        half[h] = ((r[0] + r[1]) + (r[2] + r[3]))
                + ((r[4] + r[5]) + (r[6] + r[7]));
    }
    sx2[n] = half[0] + half[1];
}

// ---------------------------------------------------------------------------
// se2[k] = numpy-pairwise sum of emb[k][d]^2.
__global__ void se2_kernel(const float* __restrict__ emb,
                           float* __restrict__ se2) {
#pragma clang fp contract(off)
    int k = blockIdx.x * 256 + threadIdx.x;
    const float* e = emb + (size_t)k * D_EMB;
    float half[2];
#pragma unroll
    for (int h = 0; h < 2; ++h) {
        float r[8];
#pragma unroll
        for (int j = 0; j < 8; ++j) {
            float v = e[h * 128 + j];
            r[j] = v * v;
        }
        for (int i = 8; i < 128; i += 8)
#pragma unroll
            for (int j = 0; j < 8; ++j) {
                float v = e[h * 128 + i + j];
                float sq = v * v;
                r[j] = r[j] + sq;
            }
        half[h] = ((r[0] + r[1]) + (r[2] + r[3]))
                + ((r[4] + r[5]) + (r[6] + r[7]));
    }
    se2[k] = half[0] + half[1];
}

// ---------------------------------------------------------------------------
// Fused distance GEMM + argmin. 512 thr = 8 waves, target 2 waves/SIMD.
// Wave w reads/writes ONLY E cols [160w, 160w+156) -> no barriers in loop.
__global__ __launch_bounds__(512, 1) void argmin_kernel(
        const float* __restrict__ z, const float* __restrict__ emb,
        const float* __restrict__ se2, const float* __restrict__ sx2,
        float* __restrict__ out_idx) {
#pragma clang fp contract(off)
    extern __shared__ float smem[];
    float* Xs    = smem;               // [256][XSTRIDE]
    float* Ebase = smem + XWORDS;      // [2][DC][EROW]

    const int t    = threadIdx.x;
    const int lane = t & 63;
    const int w    = t >> 6;           // 0..7
    const int nl   = lane & 7;
    const int ml   = lane >> 3;
    const int n0   = blockIdx.x * TN;
    const int b    = n0 >> 10;         // HW = 1024
    const int hw0  = n0 & 1023;
    const float* zb = z + (size_t)b * (D_EMB * 1024) + hw0;

    // ---- stage X (64 px x 256 d) once: 8 float4 per thread ----
    {
        int px4 = t & 15;
        int dr  = t >> 4;              // 0..31
#pragma unroll
        for (int r = 0; r < 8; ++r) {
            int d = 32 * r + dr;
            float4 v = *(const float4*)(zb + (size_t)d * 1024 + 4 * px4);
            *(float4*)&Xs[d * XSTRIDE + 4 * px4] = v;
        }
    }

    // E staging (wave-local): lane = 2*su + sh; code u = su + 32p, p in [0,4);
    // d-half sh -> global float4 at d = dc*8 + 4*sh; write col
    // ca = 160w + u + 4*(u>>4), rows 4*sh+j.  Write banks <=2-way (free).
    const int su = lane >> 1;
    const int sh = lane & 1;
    const float* embw = emb + (size_t)(128 * w) * 256;   // wave's code slice

    // prologue: stage tile 0 (kt=0, dc=0) into buffer 0 (wave-local)
    {
        float4 v[4];
#pragma unroll
        for (int p = 0; p < 4; ++p) {
            int u = su + 32 * p;
            v[p] = *(const float4*)(embw + (size_t)u * 256 + 4 * sh);
        }
#pragma unroll
        for (int p = 0; p < 4; ++p) {
            int u  = su + 32 * p;
            int ca = 160 * w + u + 4 * (u >> 4);
            float* dst = Ebase + (4 * sh) * EROW + ca;
            dst[0 * EROW] = v[p].x;
            dst[1 * EROW] = v[p].y;
            dst[2 * EROW] = v[p].z;
            dst[3 * EROW] = v[p].w;
        }
    }
    __syncthreads();   // X visible to all waves (E is wave-local anyway)

    float sx2r[8];
#pragma unroll
    for (int i = 0; i < 8; ++i)
        sx2r[i] = sx2[n0 + 8 * ml + i];

    float minv[8];
    int   mini[8];
    float acc[8][16];
#pragma unroll
    for (int i = 0; i < 8; ++i) {
        minv[i] = 3.0e38f; mini[i] = 0;
#pragma unroll
        for (int ce = 0; ce < 16; ++ce) acc[i][ce] = 0.0f;
    }

    // E read base: col = 160w + 20nl (+0..15); conflict-free (32 banks, bcast)
    const int erd = 160 * w + 20 * nl;

    for (int s = 0; s < NSTEP; ++s) {
        const bool pf = (s + 1 < NSTEP);

        // T14: issue next tile's global loads early (hide under compute)
        float4 v[4];
        if (pf) {
            const int kt1 = (s + 1) >> 5, dc1 = (s + 1) & 31;
            const float* src = embw + (size_t)kt1 * TKT * 256 + dc1 * 8 + 4 * sh;
#pragma unroll
            for (int p = 0; p < 4; ++p)
                v[p] = *(const float4*)(src + (size_t)(su + 32 * p) * 256);
        }

        // compute: DC=8 d, 128 FMA each; global d = (s&31)*8 + d ascending
        const float* Ec  = Ebase + (s & 1) * EBUF;
        const int    dg0 = (s & 31) * 8;
#pragma unroll
        for (int d = 0; d < DC; ++d) {
            const float* xr = &Xs[(dg0 + d) * XSTRIDE + 8 * ml];
            float4 xa = *(const float4*)(xr + 0);
            float4 xb = *(const float4*)(xr + 4);
            const float* er = &Ec[d * EROW + erd];
            float4 e0 = *(const float4*)(er + 0);
            float4 e1 = *(const float4*)(er + 4);
            float4 e2 = *(const float4*)(er + 8);
            float4 e3 = *(const float4*)(er + 12);
            float xv[8]  = {xa.x, xa.y, xa.z, xa.w, xb.x, xb.y, xb.z, xb.w};
            float ev[16] = {e0.x, e0.y, e0.z, e0.w, e1.x, e1.y, e1.z, e1.w,
                            e2.x, e2.y, e2.z, e2.w, e3.x, e3.y, e3.z, e3.w};
#pragma unroll
            for (int i = 0; i < 8; ++i)
#pragma unroll
                for (int ce = 0; ce < 16; ++ce)
                    acc[i][ce] = __builtin_fmaf(xv[i], ev[ce], acc[i][ce]);
        }

        // end of k-tile: dist + argmin update (k ascending), reset acc
        if ((s & 31) == 31) {
            const int kt = s >> 5;
            const int kb = kt * TKT + 128 * w + 16 * nl;
            const float* sp = &se2[kb];
            float4 s0 = *(const float4*)(sp + 0);
            float4 s1 = *(const float4*)(sp + 4);
            float4 s2 = *(const float4*)(sp + 8);
            float4 s3 = *(const float4*)(sp + 12);
            float se2v[16] = {s0.x, s0.y, s0.z, s0.w, s1.x, s1.y, s1.z, s1.w,
                              s2.x, s2.y, s2.z, s2.w, s3.x, s3.y, s3.z, s3.w};
#pragma unroll
            for (int i = 0; i < 8; ++i)
#pragma unroll
                for (int ce = 0; ce < 16; ++ce) {
                    float A = sx2r[i] + se2v[ce];
                    float dist = A - 2.0f * acc[i][ce];
                    if (dist < minv[i]) {
                        minv[i] = dist;
                        mini[i] = kb + ce;
                    }
                    acc[i][ce] = 0.0f;
                }
        }

        // write prefetched tile into the other buffer (wave-local: no barrier;
        // in-wave lgkmcnt ordering guarantees visibility at step s+1)
        if (pf) {
            float* En = Ebase + ((s + 1) & 1) * EBUF;
#pragma unroll
            for (int p = 0; p < 4; ++p) {
                int u  = su + 32 * p;
                int ca = 160 * w + u + 4 * (u >> 4);
                float* dst = En + (4 * sh) * EROW + ca;
                dst[0 * EROW] = v[p].x;
                dst[1 * EROW] = v[p].y;
                dst[2 * EROW] = v[p].z;
                dst[3 * EROW] = v[p].w;
            }
        }
    }

    // merge over the 8 nl lanes (codes) -> per-px (v,k), lexicographic
#pragma unroll
    for (int i = 0; i < 8; ++i) {
        float vv = minv[i];
        int   ki = mini[i];
#pragma unroll
        for (int m = 1; m <= 4; m <<= 1) {
            float ov = __shfl_xor(vv, m, 64);
            int   oi = __shfl_xor(ki, m, 64);
            if (ov < vv || (ov == vv && oi < ki)) { vv = ov; ki = oi; }
        }
        minv[i] = vv; mini[i] = ki;
    }

    // cross-wave merge via LDS (smem reuse -> barrier first)
    __syncthreads();
    float* Vred = smem;                 // [8][64]
    int*   Kred = (int*)(smem + 512);   // [8][64]
    if (nl == 0) {
#pragma unroll
        for (int i = 0; i < 8; ++i) {
            int pl = 8 * ml + i;
            Vred[w * 64 + pl] = minv[i];
            Kred[w * 64 + pl] = mini[i];
        }
    }
    __syncthreads();
    if (t < 64) {
        float vv = Vred[t];
        int   ki = Kred[t];
#pragma unroll
        for (int ww = 1; ww < 8; ++ww) {
            float ov = Vred[ww * 64 + t];
            int   oi = Kred[ww * 64 + t];
            if (ov < vv || (ov == vv && oi < ki)) { vv = ov; ki = oi; }
        }
        out_idx[n0 + t] = (float)ki;
    }
}

// ---------------------------------------------------------------------------
// Histogram of final indices, for perplexity.
__global__ void hist_kernel(const float* __restrict__ idxf,
                            int* __restrict__ hist) {
    int n = blockIdx.x * 256 + threadIdx.x;
    atomicAdd(&hist[(int)idxf[n]], 1);
}

// ---------------------------------------------------------------------------
// Gather quantized vectors, write z_q_x, accumulate sum of squared errors.
__global__ void quantize_kernel(const float* __restrict__ z,
                                const float* __restrict__ emb,
                                const float* __restrict__ idxf,
                                float* __restrict__ zq,
                                float* __restrict__ sse) {
    int o = (blockIdx.x * 256 + threadIdx.x) * 4;
    int hw = o & 1023;
    int c  = (o >> 10) & 255;
    int b  = o >> 18;
    int nbase = b * 1024 + hw;
    float4 x = *(const float4*)(z + o);
    float q0 = emb[(size_t)((int)idxf[nbase + 0]) * D_EMB + c];
    float q1 = emb[(size_t)((int)idxf[nbase + 1]) * D_EMB + c];
    float q2 = emb[(size_t)((int)idxf[nbase + 2]) * D_EMB + c];
    float q3 = emb[(size_t)((int)idxf[nbase + 3]) * D_EMB + c];
    float4 q = make_float4(q0, q1, q2, q3);
    *(float4*)(zq + o) = q;
    float d0 = q.x - x.x, d1 = q.y - x.y, d2 = q.z - x.z, d3 = q.w - x.w;
    float s = d0 * d0 + d1 * d1 + d2 * d2 + d3 * d3;
#pragma unroll
    for (int m = 1; m < 64; m <<= 1) s += __shfl_xor(s, m, 64);
    __shared__ float red[4];
    int lane = threadIdx.x & 63, wv = threadIdx.x >> 6;
    if (lane == 0) red[wv] = s;
    __syncthreads();
    if (threadIdx.x == 0)
        atomicAdd(sse, red[0] + red[1] + red[2] + red[3]);
}

// ---------------------------------------------------------------------------
__global__ void finalize_kernel(const int* __restrict__ hist,
                                const float* __restrict__ sse,
                                float* __restrict__ out) {
    float s = 0.0f;
    for (int i = threadIdx.x; i < K_EMB; i += 256) {
        float p = (float)hist[i] * (1.0f / (float)NPIX);
        s += p * logf(p + 1e-10f);
    }
#pragma unroll
    for (int m = 1; m < 64; m <<= 1) s += __shfl_xor(s, m, 64);
    __shared__ float red[4];
    int lane = threadIdx.x & 63, wv = threadIdx.x >> 6;
    if (lane == 0) red[wv] = s;
    __syncthreads();
    if (threadIdx.x == 0) {
        float H = -(red[0] + red[1] + red[2] + red[3]);
        out[OUT_PERP] = expf(H);
        out[OUT_LOSS] = 1.25f * sse[0] / (float)NDTOT;
    }
}

// ---------------------------------------------------------------------------
extern "C" void kernel_launch(void* const* d_in, const int* in_sizes, int n_in,
                              void* d_out, int out_size, void* d_ws, size_t ws_size,
                              hipStream_t stream) {
    const float* z   = (const float*)d_in[0];   // [16,256,32,32]
    const float* emb = (const float*)d_in[1];   // [8192,256]
    float* out = (float*)d_out;
    char*  ws  = (char*)d_ws;
    float* sse  = (float*)(ws);
    int*   hist = (int*)(ws + WS_HIST_OFF);
    float* se2  = (float*)(ws + WS_SE2_OFF);
    float* sx2  = (float*)(ws + WS_SX2_OFF);

    // allow >64KB dynamic LDS (idempotent; capture-safe host call)
    static int attr_done = 0;
    if (!attr_done) {
        (void)hipFuncSetAttribute((const void*)argmin_kernel,
                                  hipFuncAttributeMaxDynamicSharedMemorySize,
                                  SMEM_BYTES);
        attr_done = 1;
    }

    // zero sse + hist every call (graph replays don't re-poison)
    hipMemsetAsync(d_ws, 0, WS_SE2_OFF, stream);

    sx2_kernel<<<NPIX / 256, 256, 0, stream>>>(z, sx2);
    se2_kernel<<<K_EMB / 256, 256, 0, stream>>>(emb, se2);
    argmin_kernel<<<NPIX / TN, 512, SMEM_BYTES, stream>>>(z, emb, se2, sx2,
                                                          out + OUT_IDX);
    hist_kernel<<<NPIX / 256, 256, 0, stream>>>(out + OUT_IDX, hist);
    quantize_kernel<<<NDTOT / (256 * 4), 256, 0, stream>>>(
        z, emb, out + OUT_IDX, out + OUT_ZQ, sse);
    finalize_kernel<<<1, 256, 0, stream>>>(hist, sse, out);
}

// Round 9
// 1224.109 us; speedup vs baseline: 1.7367x; 1.7251x over previous
//
#include <hip/hip_runtime.h>
#include <math.h>

// VQ-VAE quantizer: N=16384 pixels, D=256, K=8192 codes.
// d_out (float32) layout: [0]=loss, [1..4194304]=z_q_x (B,C,H,W),
// [4194305]=perplexity, [4194306..+16384]=idx (as float).
//
// np-exact semantics (verified r3-r8): dist = f32(f32(sx2+se2)-f32(2*acc)),
// acc = sequential d=0..255 fp32 FMA chain; np.argmin first-min tie-break.
// r9: 256-thr blocks (4 waves, 8px x 16codes lane tile = 128 acc VGPR -- the
// 8-wave blocks of r7/r8 hit hipcc's 128-VGPR cap and spilled 5.9 GB), TN=32,
// LDS 78 KB -> 2 blocks/CU (2 waves/SIMD TLP), barrier-free wave-local E dbuf.

#define K_EMB 8192
#define D_EMB 256
#define NPIX  16384
#define NDTOT 4194304   // NPIX * D_EMB

#define OUT_LOSS 0
#define OUT_ZQ   1
#define OUT_PERP 4194305
#define OUT_IDX  4194306

// ws layout (bytes): [0] float sse; [256] int hist[8192];
// [33024] float se2[8192]; [65792] float sx2[16384]
#define WS_HIST_OFF 256
#define WS_SE2_OFF  (256 + 32768)
#define WS_SX2_OFF  (256 + 32768 + 32768)

// argmin geometry: 256 thr = 4 waves; wave w owns codes [256w,256w+256) of a
// 1024-code k-tile; lane = 16*ml + nl -> 8px x 16codes register tile.
#define TN 32                  // pixels per block (grid = 512, 2 blocks/CU)
#define TKT 1024               // codes per k-tile (4 waves x 256)
#define DC 4                   // d per step
#define NSTEP 512              // 8 kt x 64 dc
#define XSTRIDE 36             // X [256][36] floats
#define XWORDS (256 * XSTRIDE) // 9216
#define EROW 1284              // staggered row: ca = 320w + u + 4*(u>>4)
#define EBUF (DC * EROW)       // 5136 floats per buffer
#define SMEM_WORDS (XWORDS + 2 * EBUF)
#define SMEM_BYTES (SMEM_WORDS * 4)   // 77952 B (2 blocks = 155.9 KB <= 160)

// ---------------------------------------------------------------------------
// sx2[n] = numpy-pairwise sum of x[n][d]^2 (two 128-blocks, 8 accumulators).
__global__ void sx2_kernel(const float* __restrict__ z,
                           float* __restrict__ sx2) {
#pragma clang fp contract(off)
    int n = blockIdx.x * 256 + threadIdx.x;
    int b = n >> 10, hw = n & 1023;
    const float* zb = z + (size_t)b * (D_EMB * 1024) + hw;
    float half[2];
#pragma unroll
    for (int h = 0; h < 2; ++h) {
        float r[8];
#pragma unroll
        for (int j = 0; j < 8; ++j) {
            float v = zb[(size_t)(h * 128 + j) * 1024];
            r[j] = v * v;
        }
        for (int i = 8; i < 128; i += 8)
#pragma unroll
            for (int j = 0; j < 8; ++j) {
                float v = zb[(size_t)(h * 128 + i + j) * 1024];
                float sq = v * v;
                r[j] = r[j] + sq;
            }
        half[h] = ((r[0] + r[1]) + (r[2] + r[3]))
                + ((r[4] + r[5]) + (r[6] + r[7]));
    }
    sx2[n] = half[0] + half[1];
}

// ---------------------------------------------------------------------------
// se2[k] = numpy-pairwise sum of emb[k][d]^2.
__global__ void se2_kernel(const float* __restrict__ emb,
                           float* __restrict__ se2) {
#pragma clang fp contract(off)
    int k = blockIdx.x * 256 + threadIdx.x;
    const float* e = emb + (size_t)k * D_EMB;
    float half[2];
#pragma unroll
    for (int h = 0; h < 2; ++h) {
        float r[8];
#pragma unroll
        for (int j = 0; j < 8; ++j) {
            float v = e[h * 128 + j];
            r[j] = v * v;
        }
        for (int i = 8; i < 128; i += 8)
#pragma unroll
            for (int j = 0; j < 8; ++j) {
                float v = e[h * 128 + i + j];
                float sq = v * v;
                r[j] = r[j] + sq;
            }
        half[h] = ((r[0] + r[1]) + (r[2] + r[3]))
                + ((r[4] + r[5]) + (r[6] + r[7]));
    }
    se2[k] = half[0] + half[1];
}

// ---------------------------------------------------------------------------
// Fused distance GEMM + argmin. 256 thr = 4 waves; 2 blocks/CU.
// Wave w reads/writes ONLY E cols [320w, 320w+316) -> no barriers in loop.
__global__ __launch_bounds__(256, 2) void argmin_kernel(
        const float* __restrict__ z, const float* __restrict__ emb,
        const float* __restrict__ se2, const float* __restrict__ sx2,
        float* __restrict__ out_idx) {
#pragma clang fp contract(off)
    extern __shared__ float smem[];
    float* Xs    = smem;               // [256][XSTRIDE]
    float* Ebase = smem + XWORDS;      // [2][DC][EROW]

    const int t    = threadIdx.x;
    const int lane = t & 63;
    const int w    = t >> 6;           // 0..3
    const int nl   = lane & 15;        // code chunk 16*nl
    const int ml   = lane >> 4;        // px block 8*ml
    const int n0   = blockIdx.x * TN;
    const int b    = n0 >> 10;         // HW = 1024
    const int hw0  = n0 & 1023;
    const float* zb = z + (size_t)b * (D_EMB * 1024) + hw0;

    // ---- stage X (32 px x 256 d) once: 8 float4 per thread ----
    {
        int px4 = t & 7;               // 0..7 -> floats 4*px4
        int dr  = t >> 3;              // 0..31
#pragma unroll
        for (int r = 0; r < 8; ++r) {
            int d = 32 * r + dr;
            float4 v = *(const float4*)(zb + (size_t)d * 1024 + 4 * px4);
            *(float4*)&Xs[d * XSTRIDE + 4 * px4] = v;
        }
    }

    // E staging (wave-local): lane stages codes u = lane + 64p (p=0..3) of the
    // wave's 256-code slice; one float4 = 4 consecutive d of that code.
    // Write col ca = 320w + u + 4*(u>>4), rows d=0..3 (scalar, <=3-way banks).
    const float* embw = emb + (size_t)(256 * w) * 256;   // wave's code slice

    // prologue: stage tile 0 (kt=0, dc=0) into buffer 0 (wave-local)
    {
        float4 v[4];
#pragma unroll
        for (int p = 0; p < 4; ++p)
            v[p] = *(const float4*)(embw + (size_t)(lane + 64 * p) * 256);
#pragma unroll
        for (int p = 0; p < 4; ++p) {
            int u  = lane + 64 * p;
            int ca = 320 * w + u + 4 * (u >> 4);
            float* dst = Ebase + ca;
            dst[0 * EROW] = v[p].x;
            dst[1 * EROW] = v[p].y;
            dst[2 * EROW] = v[p].z;
            dst[3 * EROW] = v[p].w;
        }
    }
    __syncthreads();   // X visible to all waves (E is wave-local anyway)

    float sx2r[8];
#pragma unroll
    for (int i = 0; i < 8; ++i)
        sx2r[i] = sx2[n0 + 8 * ml + i];

    float minv[8];
    int   mini[8];
    float acc[8][16];
#pragma unroll
    for (int i = 0; i < 8; ++i) {
        minv[i] = 3.0e38f; mini[i] = 0;
#pragma unroll
        for (int ce = 0; ce < 16; ++ce) acc[i][ce] = 0.0f;
    }

    // E read base: col = 320w + 20nl (+0..15); 2-way max (free)
    const int erd = 320 * w + 20 * nl;

    for (int s = 0; s < NSTEP; ++s) {
        const bool pf = (s + 1 < NSTEP);

        // T14: issue next tile's global loads early (hide under compute)
        float4 v[4];
        if (pf) {
            const int kt1 = (s + 1) >> 6, dc1 = (s + 1) & 63;
            const float* src = embw + (size_t)kt1 * TKT * 256 + dc1 * 4;
#pragma unroll
            for (int p = 0; p < 4; ++p)
                v[p] = *(const float4*)(src + (size_t)(lane + 64 * p) * 256);
        }

        // compute: DC=4 d, 128 FMA each; global d = (s&63)*4 + d ascending
        const float* Ec  = Ebase + (s & 1) * EBUF;
        const int    dg0 = (s & 63) * 4;
#pragma unroll
        for (int d = 0; d < DC; ++d) {
            const float* xr = &Xs[(dg0 + d) * XSTRIDE + 8 * ml];
            float4 xa = *(const float4*)(xr + 0);
            float4 xb = *(const float4*)(xr + 4);
            const float* er = &Ec[d * EROW + erd];
            float4 e0 = *(const float4*)(er + 0);
            float4 e1 = *(const float4*)(er + 4);
            float4 e2 = *(const float4*)(er + 8);
            float4 e3 = *(const float4*)(er + 12);
            float xv[8]  = {xa.x, xa.y, xa.z, xa.w, xb.x, xb.y, xb.z, xb.w};
            float ev[16] = {e0.x, e0.y, e0.z, e0.w, e1.x, e1.y, e1.z, e1.w,
                            e2.x, e2.y, e2.z, e2.w, e3.x, e3.y, e3.z, e3.w};
#pragma unroll
            for (int i = 0; i < 8; ++i)
#pragma unroll
                for (int ce = 0; ce < 16; ++ce)
                    acc[i][ce] = __builtin_fmaf(xv[i], ev[ce], acc[i][ce]);
        }

        // end of k-tile: dist + argmin update (k ascending), reset acc
        if ((s & 63) == 63) {
            const int kt = s >> 6;
            const int kb = kt * TKT + 256 * w + 16 * nl;
            const float* sp = &se2[kb];
            float4 s0 = *(const float4*)(sp + 0);
            float4 s1 = *(const float4*)(sp + 4);
            float4 s2 = *(const float4*)(sp + 8);
            float4 s3 = *(const float4*)(sp + 12);
            float se2v[16] = {s0.x, s0.y, s0.z, s0.w, s1.x, s1.y, s1.z, s1.w,
                              s2.x, s2.y, s2.z, s2.w, s3.x, s3.y, s3.z, s3.w};
#pragma unroll
            for (int i = 0; i < 8; ++i)
#pragma unroll
                for (int ce = 0; ce < 16; ++ce) {
                    float A = sx2r[i] + se2v[ce];
                    float dist = A - 2.0f * acc[i][ce];
                    if (dist < minv[i]) {
                        minv[i] = dist;
                        mini[i] = kb + ce;
                    }
                    acc[i][ce] = 0.0f;
                }
        }

        // write prefetched tile into the other buffer (wave-local: no barrier;
        // in-wave lgkmcnt ordering guarantees visibility at step s+1)
        if (pf) {
            float* En = Ebase + ((s + 1) & 1) * EBUF;
#pragma unroll
            for (int p = 0; p < 4; ++p) {
                int u  = lane + 64 * p;
                int ca = 320 * w + u + 4 * (u >> 4);
                float* dst = En + ca;
                dst[0 * EROW] = v[p].x;
                dst[1 * EROW] = v[p].y;
                dst[2 * EROW] = v[p].z;
                dst[3 * EROW] = v[p].w;
            }
        }
    }

    // merge over the 16 nl lanes (codes) -> per-px (v,k), lexicographic
#pragma unroll
    for (int i = 0; i < 8; ++i) {
        float vv = minv[i];
        int   ki = mini[i];
#pragma unroll
        for (int m = 1; m <= 8; m <<= 1) {
            float ov = __shfl_xor(vv, m, 64);
            int   oi = __shfl_xor(ki, m, 64);
            if (ov < vv || (ov == vv && oi < ki)) { vv = ov; ki = oi; }
        }
        minv[i] = vv; mini[i] = ki;
    }

    // cross-wave merge via LDS (smem reuse -> barrier first)
    __syncthreads();
    float* Vred = smem;                 // [4][32]
    int*   Kred = (int*)(smem + 128);   // [4][32]
    if (nl == 0) {
#pragma unroll
        for (int i = 0; i < 8; ++i) {
            int pl = 8 * ml + i;
            Vred[w * 32 + pl] = minv[i];
            Kred[w * 32 + pl] = mini[i];
        }
    }
    __syncthreads();
    if (t < 32) {
        float vv = Vred[t];
        int   ki = Kred[t];
#pragma unroll
        for (int ww = 1; ww < 4; ++ww) {
            float ov = Vred[ww * 32 + t];
            int   oi = Kred[ww * 32 + t];
            if (ov < vv || (ov == vv && oi < ki)) { vv = ov; ki = oi; }
        }
        out_idx[n0 + t] = (float)ki;
    }
}

// ---------------------------------------------------------------------------
// Histogram of final indices, for perplexity.
__global__ void hist_kernel(const float* __restrict__ idxf,
                            int* __restrict__ hist) {
    int n = blockIdx.x * 256 + threadIdx.x;
    atomicAdd(&hist[(int)idxf[n]], 1);
}

// ---------------------------------------------------------------------------
// Gather quantized vectors, write z_q_x, accumulate sum of squared errors.
__global__ void quantize_kernel(const float* __restrict__ z,
                                const float* __restrict__ emb,
                                const float* __restrict__ idxf,
                                float* __restrict__ zq,
                                float* __restrict__ sse) {
    int o = (blockIdx.x * 256 + threadIdx.x) * 4;
    int hw = o & 1023;
    int c  = (o >> 10) & 255;
    int b  = o >> 18;
    int nbase = b * 1024 + hw;
    float4 x = *(const float4*)(z + o);
    float q0 = emb[(size_t)((int)idxf[nbase + 0]) * D_EMB + c];
    float q1 = emb[(size_t)((int)idxf[nbase + 1]) * D_EMB + c];
    float q2 = emb[(size_t)((int)idxf[nbase + 2]) * D_EMB + c];
    float q3 = emb[(size_t)((int)idxf[nbase + 3]) * D_EMB + c];
    float4 q = make_float4(q0, q1, q2, q3);
    *(float4*)(zq + o) = q;
    float d0 = q.x - x.x, d1 = q.y - x.y, d2 = q.z - x.z, d3 = q.w - x.w;
    float s = d0 * d0 + d1 * d1 + d2 * d2 + d3 * d3;
#pragma unroll
    for (int m = 1; m < 64; m <<= 1) s += __shfl_xor(s, m, 64);
    __shared__ float red[4];
    int lane = threadIdx.x & 63, wv = threadIdx.x >> 6;
    if (lane == 0) red[wv] = s;
    __syncthreads();
    if (threadIdx.x == 0)
        atomicAdd(sse, red[0] + red[1] + red[2] + red[3]);
}

// ---------------------------------------------------------------------------
__global__ void finalize_kernel(const int* __restrict__ hist,
                                const float* __restrict__ sse,
                                float* __restrict__ out) {
    float s = 0.0f;
    for (int i = threadIdx.x; i < K_EMB; i += 256) {
        float p = (float)hist[i] * (1.0f / (float)NPIX);
        s += p * logf(p + 1e-10f);
    }
#pragma unroll
    for (int m = 1; m < 64; m <<= 1) s += __shfl_xor(s, m, 64);
    __shared__ float red[4];
    int lane = threadIdx.x & 63, wv = threadIdx.x >> 6;
    if (lane == 0) red[wv] = s;
    __syncthreads();
    if (threadIdx.x == 0) {
        float H = -(red[0] + red[1] + red[2] + red[3]);
        out[OUT_PERP] = expf(H);
        out[OUT_LOSS] = 1.25f * sse[0] / (float)NDTOT;
    }
}

// ---------------------------------------------------------------------------
extern "C" void kernel_launch(void* const* d_in, const int* in_sizes, int n_in,
                              void* d_out, int out_size, void* d_ws, size_t ws_size,
                              hipStream_t stream) {
    const float* z   = (const float*)d_in[0];   // [16,256,32,32]
    const float* emb = (const float*)d_in[1];   // [8192,256]
    float* out = (float*)d_out;
    char*  ws  = (char*)d_ws;
    float* sse  = (float*)(ws);
    int*   hist = (int*)(ws + WS_HIST_OFF);
    float* se2  = (float*)(ws + WS_SE2_OFF);
    float* sx2  = (float*)(ws + WS_SX2_OFF);

    // allow >64KB dynamic LDS (idempotent; capture-safe host call)
    static int attr_done = 0;
    if (!attr_done) {
        (void)hipFuncSetAttribute((const void*)argmin_kernel,
                                  hipFuncAttributeMaxDynamicSharedMemorySize,
                                  SMEM_BYTES);
        attr_done = 1;
    }

    // zero sse + hist every call (graph replays don't re-poison)
    hipMemsetAsync(d_ws, 0, WS_SE2_OFF, stream);

    sx2_kernel<<<NPIX / 256, 256, 0, stream>>>(z, sx2);
    se2_kernel<<<K_EMB / 256, 256, 0, stream>>>(emb, se2);
    argmin_kernel<<<NPIX / TN, 256, SMEM_BYTES, stream>>>(z, emb, se2, sx2,
                                                          out + OUT_IDX);
    hist_kernel<<<NPIX / 256, 256, 0, stream>>>(out + OUT_IDX, hist);
    quantize_kernel<<<NDTOT / (256 * 4), 256, 0, stream>>>(
        z, emb, out + OUT_IDX, out + OUT_ZQ, sse);
    finalize_kernel<<<1, 256, 0, stream>>>(hist, sse, out);
}

// Round 10
// 1006.565 us; speedup vs baseline: 2.1120x; 1.2161x over previous
//
#include <hip/hip_runtime.h>
#include <math.h>

// VQ-VAE quantizer: N=16384 pixels, D=256, K=8192 codes.
// d_out (float32) layout: [0]=loss, [1..4194304]=z_q_x (B,C,H,W),
// [4194305]=perplexity, [4194306..+16384]=idx (as float).
//
// np-exact semantics (verified r3-r9): dist = f32(f32(sx2+se2)-f32(2*acc)),
// acc = sequential d=0..255 fp32 FMA chain; np.argmin first-min tie-break.
// r10: X operand moved to the SCALAR pipe (wave-uniform px block ->
// s_load_dwordx8, SGPR src0 in v_fma). LDS carries only E (2 conflict-free
// ds_read_b128 per d) -> first FMA-bound config (LDS:FMA = 0.94).
// 512 thr = 8 waves = (px-quarter) x (code-half); 16 waves/CU (2 blocks).

#define K_EMB 8192
#define D_EMB 256
#define NPIX  16384
#define NDTOT 4194304   // NPIX * D_EMB

#define OUT_LOSS 0
#define OUT_ZQ   1
#define OUT_PERP 4194305
#define OUT_IDX  4194306

// ws layout (bytes): [0] float sse; [256] int hist[8192];
// [33024] float se2[8192]; [65792] float sx2[16384]
#define WS_HIST_OFF 256
#define WS_SE2_OFF  (256 + 32768)
#define WS_SX2_OFF  (256 + 32768 + 32768)

// argmin geometry
#define TN 32                  // pixels per block (grid = 512, 2 blocks/CU)
#define TKT 1024               // codes per k-tile
#define DC 8                   // d per step
#define NSTEP 256              // 8 kt x 32 dc
#define EROWF 1032             // E row floats (1024 + 8 pad)
#define EBUFW (DC * EROWF)     // 8256 floats per buffer
#define SMEM_BYTES (2 * EBUFW * 4)   // 66048 B (2 blocks = 132 KB <= 160)

// ---------------------------------------------------------------------------
// sx2[n] = numpy-pairwise sum of x[n][d]^2 (two 128-blocks, 8 accumulators).
__global__ void sx2_kernel(const float* __restrict__ z,
                           float* __restrict__ sx2) {
#pragma clang fp contract(off)
    int n = blockIdx.x * 256 + threadIdx.x;
    int b = n >> 10, hw = n & 1023;
    const float* zb = z + (size_t)b * (D_EMB * 1024) + hw;
    float half[2];
#pragma unroll
    for (int h = 0; h < 2; ++h) {
        float r[8];
#pragma unroll
        for (int j = 0; j < 8; ++j) {
            float v = zb[(size_t)(h * 128 + j) * 1024];
            r[j] = v * v;
        }
        for (int i = 8; i < 128; i += 8)
#pragma unroll
            for (int j = 0; j < 8; ++j) {
                float v = zb[(size_t)(h * 128 + i + j) * 1024];
                float sq = v * v;
                r[j] = r[j] + sq;
            }
        half[h] = ((r[0] + r[1]) + (r[2] + r[3]))
                + ((r[4] + r[5]) + (r[6] + r[7]));
    }
    sx2[n] = half[0] + half[1];
}

// ---------------------------------------------------------------------------
// se2[k] = numpy-pairwise sum of emb[k][d]^2.
__global__ void se2_kernel(const float* __restrict__ emb,
                           float* __restrict__ se2) {
#pragma clang fp contract(off)
    int k = blockIdx.x * 256 + threadIdx.x;
    const float* e = emb + (size_t)k * D_EMB;
    float half[2];
#pragma unroll
    for (int h = 0; h < 2; ++h) {
        float r[8];
#pragma unroll
        for (int j = 0; j < 8; ++j) {
            float v = e[h * 128 + j];
            r[j] = v * v;
        }
        for (int i = 8; i < 128; i += 8)
#pragma unroll
            for (int j = 0; j < 8; ++j) {
                float v = e[h * 128 + i + j];
                float sq = v * v;
                r[j] = r[j] + sq;
            }
        half[h] = ((r[0] + r[1]) + (r[2] + r[3]))
                + ((r[4] + r[5]) + (r[6] + r[7]));
    }
    se2[k] = half[0] + half[1];
}

// ---------------------------------------------------------------------------
// Fused distance GEMM + argmin. 512 thr = 8 waves; 2 blocks/CU (16 waves).
// Wave w: px-quarter q=w>>1 (8 px), code-half ch=w&1 (512 codes of the tile).
// Lane: 8 px (registers, SAME px for all lanes) x 8 codes (8*lane..+8).
// X[px][d] is wave-uniform -> scalar loads, SGPR FMA operand.
// E double-buffered in LDS [2][8][1032]; cooperative staging + 2 barriers.
__global__ __launch_bounds__(512) void argmin_kernel(
        const float* __restrict__ z, const float* __restrict__ emb,
        const float* __restrict__ se2, const float* __restrict__ sx2,
        float* __restrict__ out_idx) {
#pragma clang fp contract(off)
    extern __shared__ float smem[];
    float* Eb = smem;                  // [2][DC][EROWF]

    const int t    = threadIdx.x;
    const int lane = t & 63;
    const int w    = t >> 6;           // 0..7
    const int ch   = w & 1;            // code half
    const int n0   = blockIdx.x * TN;
    const int b    = n0 >> 10;         // HW = 1024
    const int hw0  = n0 & 1023;
    const float* zb = z + (size_t)b * (D_EMB * 1024) + hw0;

    // wave-uniform px block base (readfirstlane forces SGPR/scalar loads)
    const int qu = __builtin_amdgcn_readfirstlane(w >> 1);
    const float* xw = zb + 8 * qu;     // X[px i][d] = xw[d*1024 + i]

    // staging: wave stages codes [128w,128w+128) of the tile.
    // lane -> (su = lane>>1, sh = lane&1): code su+32p, d-quad 4*sh.
    // global 32B-coalesced (2 lanes/code); LDS write col 128w+su+32p,
    // rows 4*sh+j -> 2-way banks (free), write2-pairable (32-float offsets).
    const int su = lane >> 1;
    const int sh = lane & 1;
    const float* embs = emb + (size_t)(128 * w + su) * 256 + 4 * sh;

    // E read base: col = 512*ch + 8*lane (contiguous b128, conflict-free)
    const int erd = 512 * ch + 8 * lane;

    // prologue: stage tile 0 (kt=0, dc=0) into buffer 0
    {
        float4 v[4];
#pragma unroll
        for (int p = 0; p < 4; ++p)
            v[p] = *(const float4*)(embs + (size_t)(32 * p) * 256);
        float* wb = Eb + 128 * w + su;
#pragma unroll
        for (int j = 0; j < 4; ++j) {
            float* r = wb + (4 * sh + j) * EROWF;
            float a0 = (j == 0) ? v[0].x : (j == 1) ? v[0].y : (j == 2) ? v[0].z : v[0].w;
            float a1 = (j == 0) ? v[1].x : (j == 1) ? v[1].y : (j == 2) ? v[1].z : v[1].w;
            float a2 = (j == 0) ? v[2].x : (j == 1) ? v[2].y : (j == 2) ? v[2].z : v[2].w;
            float a3 = (j == 0) ? v[3].x : (j == 1) ? v[3].y : (j == 2) ? v[3].z : v[3].w;
            r[0] = a0; r[32] = a1; r[64] = a2; r[96] = a3;
        }
    }
    __syncthreads();

    float sx2r[8];
#pragma unroll
    for (int i = 0; i < 8; ++i)
        sx2r[i] = sx2[n0 + 8 * qu + i];

    float minv[8];
    int   mini[8];
    float acc[8][8];
#pragma unroll
    for (int i = 0; i < 8; ++i) {
        minv[i] = 3.0e38f; mini[i] = 0;
#pragma unroll
        for (int ce = 0; ce < 8; ++ce) acc[i][ce] = 0.0f;
    }

    for (int s = 0; s < NSTEP; ++s) {
        const bool pf = (s + 1 < NSTEP);

        // T14: issue next tile's global loads early
        float4 v[4];
        if (pf) {
            const int kt1 = (s + 1) >> 5, dc1 = (s + 1) & 31;
            const float* src = embs + (size_t)kt1 * TKT * 256 + dc1 * 8;
#pragma unroll
            for (int p = 0; p < 4; ++p)
                v[p] = *(const float4*)(src + (size_t)(32 * p) * 256);
        }

        // compute: DC=8 d; per d: 8 scalar X loads + 2 ds_read_b128 + 64 FMA
        const float* Ec  = Eb + (s & 1) * EBUFW;
        const int    dg0 = (s & 31) * 8;   // d within this kt, ascending
#pragma unroll
        for (int dh = 0; dh < 2; ++dh) {
            float xs[4][8];
#pragma unroll
            for (int dd = 0; dd < 4; ++dd)
#pragma unroll
                for (int i = 0; i < 8; ++i)
                    xs[dd][i] = xw[(size_t)(dg0 + 4 * dh + dd) * 1024 + i];
#pragma unroll
            for (int dd = 0; dd < 4; ++dd) {
                const int di = 4 * dh + dd;
                const float* er = &Ec[di * EROWF + erd];
                float4 e0 = *(const float4*)(er + 0);
                float4 e1 = *(const float4*)(er + 4);
                float ev[8] = {e0.x, e0.y, e0.z, e0.w,
                               e1.x, e1.y, e1.z, e1.w};
#pragma unroll
                for (int i = 0; i < 8; ++i)
#pragma unroll
                    for (int ce = 0; ce < 8; ++ce)
                        acc[i][ce] = __builtin_fmaf(
                            xs[dd][i], ev[ce], acc[i][ce]);
            }
        }

        // end of k-tile: dist + argmin update (k ascending), reset acc
        if ((s & 31) == 31) {
            const int kt = s >> 5;
            const int kb = kt * TKT + 512 * ch + 8 * lane;
            float4 s0 = *(const float4*)&se2[kb];
            float4 s1 = *(const float4*)&se2[kb + 4];
            float se2v[8] = {s0.x, s0.y, s0.z, s0.w,
                             s1.x, s1.y, s1.z, s1.w};
#pragma unroll
            for (int i = 0; i < 8; ++i)
#pragma unroll
                for (int ce = 0; ce < 8; ++ce) {
                    float A = sx2r[i] + se2v[ce];
                    float dist = A - 2.0f * acc[i][ce];
                    if (dist < minv[i]) {
                        minv[i] = dist;
                        mini[i] = kb + ce;
                    }
                    acc[i][ce] = 0.0f;
                }
        }

        __syncthreads();   // all waves done reading buffer (s&1)... and (s+1)&1 from s-1

        // write prefetched tile into the other buffer
        if (pf) {
            float* En = Eb + ((s + 1) & 1) * EBUFW;
            float* wb = En + 128 * w + su;
#pragma unroll
            for (int j = 0; j < 4; ++j) {
                float* r = wb + (4 * sh + j) * EROWF;
                float a0 = (j == 0) ? v[0].x : (j == 1) ? v[0].y : (j == 2) ? v[0].z : v[0].w;
                float a1 = (j == 0) ? v[1].x : (j == 1) ? v[1].y : (j == 2) ? v[1].z : v[1].w;
                float a2 = (j == 0) ? v[2].x : (j == 1) ? v[2].y : (j == 2) ? v[2].z : v[2].w;
                float a3 = (j == 0) ? v[3].x : (j == 1) ? v[3].y : (j == 2) ? v[3].z : v[3].w;
                r[0] = a0; r[32] = a1; r[64] = a2; r[96] = a3;
            }
        }
        __syncthreads();
    }

    // in-wave merge across all 64 lanes (disjoint codes, same px set)
#pragma unroll
    for (int i = 0; i < 8; ++i) {
        float vv = minv[i];
        int   ki = mini[i];
#pragma unroll
        for (int m = 1; m <= 32; m <<= 1) {
            float ov = __shfl_xor(vv, m, 64);
            int   oi = __shfl_xor(ki, m, 64);
            if (ov < vv || (ov == vv && oi < ki)) { vv = ov; ki = oi; }
        }
        minv[i] = vv; mini[i] = ki;
    }

    // cross-wave merge: code-half partners (2q, 2q+1) share the px set
    __syncthreads();
    float* Vred = smem;                 // [8 waves][8 px]
    int*   Kred = (int*)(smem + 64);
    if (lane == 0) {
#pragma unroll
        for (int i = 0; i < 8; ++i) {
            Vred[w * 8 + i] = minv[i];
            Kred[w * 8 + i] = mini[i];
        }
    }
    __syncthreads();
    if (t < 32) {
        int qq = t >> 3, i = t & 7;
        float v0 = Vred[(2 * qq) * 8 + i];
        int   k0 = Kred[(2 * qq) * 8 + i];
        float v1 = Vred[(2 * qq + 1) * 8 + i];
        int   k1 = Kred[(2 * qq + 1) * 8 + i];
        if (v1 < v0 || (v1 == v0 && k1 < k0)) { v0 = v1; k0 = k1; }
        out_idx[n0 + 8 * qq + i] = (float)k0;
    }
}

// ---------------------------------------------------------------------------
// Histogram of final indices, for perplexity.
__global__ void hist_kernel(const float* __restrict__ idxf,
                            int* __restrict__ hist) {
    int n = blockIdx.x * 256 + threadIdx.x;
    atomicAdd(&hist[(int)idxf[n]], 1);
}

// ---------------------------------------------------------------------------
// Gather quantized vectors, write z_q_x, accumulate sum of squared errors.
__global__ void quantize_kernel(const float* __restrict__ z,
                                const float* __restrict__ emb,
                                const float* __restrict__ idxf,
                                float* __restrict__ zq,
                                float* __restrict__ sse) {
    int o = (blockIdx.x * 256 + threadIdx.x) * 4;
    int hw = o & 1023;
    int c  = (o >> 10) & 255;
    int b  = o >> 18;
    int nbase = b * 1024 + hw;
    float4 x = *(const float4*)(z + o);
    float q0 = emb[(size_t)((int)idxf[nbase + 0]) * D_EMB + c];
    float q1 = emb[(size_t)((int)idxf[nbase + 1]) * D_EMB + c];
    float q2 = emb[(size_t)((int)idxf[nbase + 2]) * D_EMB + c];
    float q3 = emb[(size_t)((int)idxf[nbase + 3]) * D_EMB + c];
    float4 q = make_float4(q0, q1, q2, q3);
    *(float4*)(zq + o) = q;
    float d0 = q.x - x.x, d1 = q.y - x.y, d2 = q.z - x.z, d3 = q.w - x.w;
    float s = d0 * d0 + d1 * d1 + d2 * d2 + d3 * d3;
#pragma unroll
    for (int m = 1; m < 64; m <<= 1) s += __shfl_xor(s, m, 64);
    __shared__ float red[4];
    int lane = threadIdx.x & 63, wv = threadIdx.x >> 6;
    if (lane == 0) red[wv] = s;
    __syncthreads();
    if (threadIdx.x == 0)
        atomicAdd(sse, red[0] + red[1] + red[2] + red[3]);
}

// ---------------------------------------------------------------------------
__global__ void finalize_kernel(const int* __restrict__ hist,
                                const float* __restrict__ sse,
                                float* __restrict__ out) {
    float s = 0.0f;
    for (int i = threadIdx.x; i < K_EMB; i += 256) {
        float p = (float)hist[i] * (1.0f / (float)NPIX);
        s += p * logf(p + 1e-10f);
    }
#pragma unroll
    for (int m = 1; m < 64; m <<= 1) s += __shfl_xor(s, m, 64);
    __shared__ float red[4];
    int lane = threadIdx.x & 63, wv = threadIdx.x >> 6;
    if (lane == 0) red[wv] = s;
    __syncthreads();
    if (threadIdx.x == 0) {
        float H = -(red[0] + red[1] + red[2] + red[3]);
        out[OUT_PERP] = expf(H);
        out[OUT_LOSS] = 1.25f * sse[0] / (float)NDTOT;
    }
}

// ---------------------------------------------------------------------------
extern "C" void kernel_launch(void* const* d_in, const int* in_sizes, int n_in,
                              void* d_out, int out_size, void* d_ws, size_t ws_size,
                              hipStream_t stream) {
    const float* z   = (const float*)d_in[0];   // [16,256,32,32]
    const float* emb = (const float*)d_in[1];   // [8192,256]
    float* out = (float*)d_out;
    char*  ws  = (char*)d_ws;
    float* sse  = (float*)(ws);
    int*   hist = (int*)(ws + WS_HIST_OFF);
    float* se2  = (float*)(ws + WS_SE2_OFF);
    float* sx2  = (float*)(ws + WS_SX2_OFF);

    // allow >64KB dynamic LDS (idempotent; capture-safe host call)
    static int attr_done = 0;
    if (!attr_done) {
        (void)hipFuncSetAttribute((const void*)argmin_kernel,
                                  hipFuncAttributeMaxDynamicSharedMemorySize,
                                  SMEM_BYTES);
        attr_done = 1;
    }

    // zero sse + hist every call (graph replays don't re-poison)
    hipMemsetAsync(d_ws, 0, WS_SE2_OFF, stream);

    sx2_kernel<<<NPIX / 256, 256, 0, stream>>>(z, sx2);
    se2_kernel<<<K_EMB / 256, 256, 0, stream>>>(emb, se2);
    argmin_kernel<<<NPIX / TN, 512, SMEM_BYTES, stream>>>(z, emb, se2, sx2,
                                                          out + OUT_IDX);
    hist_kernel<<<NPIX / 256, 256, 0, stream>>>(out + OUT_IDX, hist);
    quantize_kernel<<<NDTOT / (256 * 4), 256, 0, stream>>>(
        z, emb, out + OUT_IDX, out + OUT_ZQ, sse);
    finalize_kernel<<<1, 256, 0, stream>>>(hist, sse, out);
}

// Round 11
// 920.742 us; speedup vs baseline: 2.3089x; 1.0932x over previous
//
#include <hip/hip_runtime.h>
#include <math.h>

// VQ-VAE quantizer: N=16384 pixels, D=256, K=8192 codes.
// d_out (float32) layout: [0]=loss, [1..4194304]=z_q_x (B,C,H,W),
// [4194305]=perplexity, [4194306..+16384]=idx (as float).
//
// np-exact semantics (verified r3-r10): dist = f32(f32(sx2+se2)-f32(2*acc)),
// acc = sequential d=0..255 fp32 FMA chain; np.argmin first-min tie-break.
// r11 = r10 + (a) conflict-free E reads: lane owns codes {4l, 256+4l} so each
// ds_read_b128 is a contiguous 1KB wave access (r10's 8l stride was 2-way
// serialized: 1.0e8 conflict cycles); (b) v_pk_fma_f32 via float2
// __builtin_elementwise_fma (fp32 spec rate 157 TF is PACKED; scalar fma
// peaks at 78.6 TF). Packing is across codes -> per-chain rounding identical.

#define K_EMB 8192
#define D_EMB 256
#define NPIX  16384
#define NDTOT 4194304   // NPIX * D_EMB

#define OUT_LOSS 0
#define OUT_ZQ   1
#define OUT_PERP 4194305
#define OUT_IDX  4194306

// ws layout (bytes): [0] float sse; [256] int hist[8192];
// [33024] float se2[8192]; [65792] float sx2[16384]
#define WS_HIST_OFF 256
#define WS_SE2_OFF  (256 + 32768)
#define WS_SX2_OFF  (256 + 32768 + 32768)

// argmin geometry
#define TN 32                  // pixels per block (grid = 512, 2 blocks/CU)
#define TKT 1024               // codes per k-tile
#define DC 8                   // d per step
#define NSTEP 256              // 8 kt x 32 dc
#define EROWF 1032             // E row floats (1024 + 8 pad)
#define EBUFW (DC * EROWF)     // 8256 floats per buffer
#define SMEM_BYTES (2 * EBUFW * 4)   // 66048 B (2 blocks = 132 KB <= 160)

typedef float v2f __attribute__((ext_vector_type(2)));

// ---------------------------------------------------------------------------
// sx2[n] = numpy-pairwise sum of x[n][d]^2 (two 128-blocks, 8 accumulators).
__global__ void sx2_kernel(const float* __restrict__ z,
                           float* __restrict__ sx2) {
#pragma clang fp contract(off)
    int n = blockIdx.x * 256 + threadIdx.x;
    int b = n >> 10, hw = n & 1023;
    const float* zb = z + (size_t)b * (D_EMB * 1024) + hw;
    float half[2];
#pragma unroll
    for (int h = 0; h < 2; ++h) {
        float r[8];
#pragma unroll
        for (int j = 0; j < 8; ++j) {
            float v = zb[(size_t)(h * 128 + j) * 1024];
            r[j] = v * v;
        }
        for (int i = 8; i < 128; i += 8)
#pragma unroll
            for (int j = 0; j < 8; ++j) {
                float v = zb[(size_t)(h * 128 + i + j) * 1024];
                float sq = v * v;
                r[j] = r[j] + sq;
            }
        half[h] = ((r[0] + r[1]) + (r[2] + r[3]))
                + ((r[4] + r[5]) + (r[6] + r[7]));
    }
    sx2[n] = half[0] + half[1];
}

// ---------------------------------------------------------------------------
// se2[k] = numpy-pairwise sum of emb[k][d]^2.
__global__ void se2_kernel(const float* __restrict__ emb,
                           float* __restrict__ se2) {
#pragma clang fp contract(off)
    int k = blockIdx.x * 256 + threadIdx.x;
    const float* e = emb + (size_t)k * D_EMB;
    float half[2];
#pragma unroll
    for (int h = 0; h < 2; ++h) {
        float r[8];
#pragma unroll
        for (int j = 0; j < 8; ++j) {
            float v = e[h * 128 + j];
            r[j] = v * v;
        }
        for (int i = 8; i < 128; i += 8)
#pragma unroll
            for (int j = 0; j < 8; ++j) {
                float v = e[h * 128 + i + j];
                float sq = v * v;
                r[j] = r[j] + sq;
            }
        half[h] = ((r[0] + r[1]) + (r[2] + r[3]))
                + ((r[4] + r[5]) + (r[6] + r[7]));
    }
    se2[k] = half[0] + half[1];
}

// ---------------------------------------------------------------------------
// Fused distance GEMM + argmin. 512 thr = 8 waves; 2 blocks/CU (16 waves).
// Wave w: px-quarter q=w>>1 (8 px), code-half ch=w&1 (512 codes of the tile).
// Lane: 8 px (wave-uniform -> scalar X) x 8 codes {4l..4l+3, 256+4l..+3}.
// E double-buffered in LDS [2][8][1032]; cooperative staging + 2 barriers.
__global__ __launch_bounds__(512) void argmin_kernel(
        const float* __restrict__ z, const float* __restrict__ emb,
        const float* __restrict__ se2, const float* __restrict__ sx2,
        float* __restrict__ out_idx) {
#pragma clang fp contract(off)
    extern __shared__ float smem[];
    float* Eb = smem;                  // [2][DC][EROWF]

    const int t    = threadIdx.x;
    const int lane = t & 63;
    const int w    = t >> 6;           // 0..7
    const int ch   = w & 1;            // code half
    const int n0   = blockIdx.x * TN;
    const int b    = n0 >> 10;         // HW = 1024
    const int hw0  = n0 & 1023;
    const float* zb = z + (size_t)b * (D_EMB * 1024) + hw0;

    // wave-uniform px block base (readfirstlane forces SGPR/scalar loads)
    const int qu = __builtin_amdgcn_readfirstlane(w >> 1);
    const float* xw = zb + 8 * qu;     // X[px i][d] = xw[d*1024 + i]

    // staging: wave stages codes [128w,128w+128) of the tile (unchanged r10;
    // write banks 2-way = free, global 32B-coalesced).
    const int su = lane >> 1;
    const int sh = lane & 1;
    const float* embs = emb + (size_t)(128 * w + su) * 256 + 4 * sh;

    // E read base: codes 512*ch + 4*lane and +256 -> byte stride 16*lane,
    // each b128 a contiguous 1KB wave access (conflict-free).
    const int erd = 512 * ch + 4 * lane;

    // prologue: stage tile 0 (kt=0, dc=0) into buffer 0
    {
        float4 v[4];
#pragma unroll
        for (int p = 0; p < 4; ++p)
            v[p] = *(const float4*)(embs + (size_t)(32 * p) * 256);
        float* wb = Eb + 128 * w + su;
#pragma unroll
        for (int j = 0; j < 4; ++j) {
            float* r = wb + (4 * sh + j) * EROWF;
            float a0 = (j == 0) ? v[0].x : (j == 1) ? v[0].y : (j == 2) ? v[0].z : v[0].w;
            float a1 = (j == 0) ? v[1].x : (j == 1) ? v[1].y : (j == 2) ? v[1].z : v[1].w;
            float a2 = (j == 0) ? v[2].x : (j == 1) ? v[2].y : (j == 2) ? v[2].z : v[2].w;
            float a3 = (j == 0) ? v[3].x : (j == 1) ? v[3].y : (j == 2) ? v[3].z : v[3].w;
            r[0] = a0; r[32] = a1; r[64] = a2; r[96] = a3;
        }
    }
    __syncthreads();

    float sx2r[8];
#pragma unroll
    for (int i = 0; i < 8; ++i)
        sx2r[i] = sx2[n0 + 8 * qu + i];

    float minv[8];
    int   mini[8];
    v2f   acc[8][4];                   // [px][code-pair]; pairs 0-1: codes
                                       // 4l..4l+3, pairs 2-3: 256+4l..+3
#pragma unroll
    for (int i = 0; i < 8; ++i) {
        minv[i] = 3.0e38f; mini[i] = 0;
#pragma unroll
        for (int ce = 0; ce < 4; ++ce) acc[i][ce] = (v2f){0.0f, 0.0f};
    }

    for (int s = 0; s < NSTEP; ++s) {
        const bool pf = (s + 1 < NSTEP);

        // T14: issue next tile's global loads early
        float4 v[4];
        if (pf) {
            const int kt1 = (s + 1) >> 5, dc1 = (s + 1) & 31;
            const float* src = embs + (size_t)kt1 * TKT * 256 + dc1 * 8;
#pragma unroll
            for (int p = 0; p < 4; ++p)
                v[p] = *(const float4*)(src + (size_t)(32 * p) * 256);
        }

        // compute: DC=8 d; per d: 8 scalar X loads + 2 ds_read_b128 + 32 pk-FMA
        const float* Ec  = Eb + (s & 1) * EBUFW;
        const int    dg0 = (s & 31) * 8;   // d within this kt, ascending
#pragma unroll
        for (int dh = 0; dh < 2; ++dh) {
            float xs[4][8];
#pragma unroll
            for (int dd = 0; dd < 4; ++dd)
#pragma unroll
                for (int i = 0; i < 8; ++i)
                    xs[dd][i] = xw[(size_t)(dg0 + 4 * dh + dd) * 1024 + i];
#pragma unroll
            for (int dd = 0; dd < 4; ++dd) {
                const int di = 4 * dh + dd;
                const float* er = &Ec[di * EROWF + erd];
                float4 e0 = *(const float4*)(er + 0);
                float4 e1 = *(const float4*)(er + 256);
                v2f ev[4] = {{e0.x, e0.y}, {e0.z, e0.w},
                             {e1.x, e1.y}, {e1.z, e1.w}};
#pragma unroll
                for (int i = 0; i < 8; ++i) {
                    v2f xx = {xs[dd][i], xs[dd][i]};
#pragma unroll
                    for (int ce = 0; ce < 4; ++ce)
                        acc[i][ce] = __builtin_elementwise_fma(
                            xx, ev[ce], acc[i][ce]);
                }
            }
        }

        // end of k-tile: dist + argmin update (k ascending), reset acc
        if ((s & 31) == 31) {
            const int kt = s >> 5;
            const int kb = kt * TKT + 512 * ch + 4 * lane;
            float4 s0 = *(const float4*)&se2[kb];         // codes kb..kb+3
            float4 s1 = *(const float4*)&se2[kb + 256];   // codes kb+256..+3
            float se2v[8] = {s0.x, s0.y, s0.z, s0.w,
                             s1.x, s1.y, s1.z, s1.w};
#pragma unroll
            for (int i = 0; i < 8; ++i) {
#pragma unroll
                for (int ce = 0; ce < 8; ++ce) {
                    // ce 0..3 -> codes kb+ce; ce 4..7 -> kb+256+(ce-4);
                    // ascending k within the lane in both blocks.
                    float a = (ce & 1) ? acc[i][ce >> 1].y
                                       : acc[i][ce >> 1].x;
                    int   k = kb + ((ce < 4) ? ce : (252 + ce));
                    float A = sx2r[i] + se2v[ce];
                    float dist = A - 2.0f * a;
                    if (dist < minv[i]) {
                        minv[i] = dist;
                        mini[i] = k;
                    }
                }
#pragma unroll
                for (int ce = 0; ce < 4; ++ce)
                    acc[i][ce] = (v2f){0.0f, 0.0f};
            }
        }

        __syncthreads();

        // write prefetched tile into the other buffer
        if (pf) {
            float* En = Eb + ((s + 1) & 1) * EBUFW;
            float* wb = En + 128 * w + su;
#pragma unroll
            for (int j = 0; j < 4; ++j) {
                float* r = wb + (4 * sh + j) * EROWF;
                float a0 = (j == 0) ? v[0].x : (j == 1) ? v[0].y : (j == 2) ? v[0].z : v[0].w;
                float a1 = (j == 0) ? v[1].x : (j == 1) ? v[1].y : (j == 2) ? v[1].z : v[1].w;
                float a2 = (j == 0) ? v[2].x : (j == 1) ? v[2].y : (j == 2) ? v[2].z : v[2].w;
                float a3 = (j == 0) ? v[3].x : (j == 1) ? v[3].y : (j == 2) ? v[3].z : v[3].w;
                r[0] = a0; r[32] = a1; r[64] = a2; r[96] = a3;
            }
        }
        __syncthreads();
    }

    // in-wave merge across all 64 lanes (disjoint codes, same px set)
#pragma unroll
    for (int i = 0; i < 8; ++i) {
        float vv = minv[i];
        int   ki = mini[i];
#pragma unroll
        for (int m = 1; m <= 32; m <<= 1) {
            float ov = __shfl_xor(vv, m, 64);
            int   oi = __shfl_xor(ki, m, 64);
            if (ov < vv || (ov == vv && oi < ki)) { vv = ov; ki = oi; }
        }
        minv[i] = vv; mini[i] = ki;
    }

    // cross-wave merge: code-half partners (2q, 2q+1) share the px set
    __syncthreads();
    float* Vred = smem;                 // [8 waves][8 px]
    int*   Kred = (int*)(smem + 64);
    if (lane == 0) {
#pragma unroll
        for (int i = 0; i < 8; ++i) {
            Vred[w * 8 + i] = minv[i];
            Kred[w * 8 + i] = mini[i];
        }
    }
    __syncthreads();
    if (t < 32) {
        int qq = t >> 3, i = t & 7;
        float v0 = Vred[(2 * qq) * 8 + i];
        int   k0 = Kred[(2 * qq) * 8 + i];
        float v1 = Vred[(2 * qq + 1) * 8 + i];
        int   k1 = Kred[(2 * qq + 1) * 8 + i];
        if (v1 < v0 || (v1 == v0 && k1 < k0)) { v0 = v1; k0 = k1; }
        out_idx[n0 + 8 * qq + i] = (float)k0;
    }
}

// ---------------------------------------------------------------------------
// Histogram of final indices, for perplexity.
__global__ void hist_kernel(const float* __restrict__ idxf,
                            int* __restrict__ hist) {
    int n = blockIdx.x * 256 + threadIdx.x;
    atomicAdd(&hist[(int)idxf[n]], 1);
}

// ---------------------------------------------------------------------------
// Gather quantized vectors, write z_q_x, accumulate sum of squared errors.
__global__ void quantize_kernel(const float* __restrict__ z,
                                const float* __restrict__ emb,
                                const float* __restrict__ idxf,
                                float* __restrict__ zq,
                                float* __restrict__ sse) {
    int o = (blockIdx.x * 256 + threadIdx.x) * 4;
    int hw = o & 1023;
    int c  = (o >> 10) & 255;
    int b  = o >> 18;
    int nbase = b * 1024 + hw;
    float4 x = *(const float4*)(z + o);
    float q0 = emb[(size_t)((int)idxf[nbase + 0]) * D_EMB + c];
    float q1 = emb[(size_t)((int)idxf[nbase + 1]) * D_EMB + c];
    float q2 = emb[(size_t)((int)idxf[nbase + 2]) * D_EMB + c];
    float q3 = emb[(size_t)((int)idxf[nbase + 3]) * D_EMB + c];
    float4 q = make_float4(q0, q1, q2, q3);
    *(float4*)(zq + o) = q;
    float d0 = q.x - x.x, d1 = q.y - x.y, d2 = q.z - x.z, d3 = q.w - x.w;
    float s = d0 * d0 + d1 * d1 + d2 * d2 + d3 * d3;
#pragma unroll
    for (int m = 1; m < 64; m <<= 1) s += __shfl_xor(s, m, 64);
    __shared__ float red[4];
    int lane = threadIdx.x & 63, wv = threadIdx.x >> 6;
    if (lane == 0) red[wv] = s;
    __syncthreads();
    if (threadIdx.x == 0)
        atomicAdd(sse, red[0] + red[1] + red[2] + red[3]);
}

// ---------------------------------------------------------------------------
__global__ void finalize_kernel(const int* __restrict__ hist,
                                const float* __restrict__ sse,
                                float* __restrict__ out) {
    float s = 0.0f;
    for (int i = threadIdx.x; i < K_EMB; i += 256) {
        float p = (float)hist[i] * (1.0f / (float)NPIX);
        s += p * logf(p + 1e-10f);
    }
#pragma unroll
    for (int m = 1; m < 64; m <<= 1) s += __shfl_xor(s, m, 64);
    __shared__ float red[4];
    int lane = threadIdx.x & 63, wv = threadIdx.x >> 6;
    if (lane == 0) red[wv] = s;
    __syncthreads();
    if (threadIdx.x == 0) {
        float H = -(red[0] + red[1] + red[2] + red[3]);
        out[OUT_PERP] = expf(H);
        out[OUT_LOSS] = 1.25f * sse[0] / (float)NDTOT;
    }
}

// ---------------------------------------------------------------------------
extern "C" void kernel_launch(void* const* d_in, const int* in_sizes, int n_in,
                              void* d_out, int out_size, void* d_ws, size_t ws_size,
                              hipStream_t stream) {
    const float* z   = (const float*)d_in[0];   // [16,256,32,32]
    const float* emb = (const float*)d_in[1];   // [8192,256]
    float* out = (float*)d_out;
    char*  ws  = (char*)d_ws;
    float* sse  = (float*)(ws);
    int*   hist = (int*)(ws + WS_HIST_OFF);
    float* se2  = (float*)(ws + WS_SE2_OFF);
    float* sx2  = (float*)(ws + WS_SX2_OFF);

    // allow >64KB dynamic LDS (idempotent; capture-safe host call)
    static int attr_done = 0;
    if (!attr_done) {
        (void)hipFuncSetAttribute((const void*)argmin_kernel,
                                  hipFuncAttributeMaxDynamicSharedMemorySize,
                                  SMEM_BYTES);
        attr_done = 1;
    }

    // zero sse + hist every call (graph replays don't re-poison)
    hipMemsetAsync(d_ws, 0, WS_SE2_OFF, stream);

    sx2_kernel<<<NPIX / 256, 256, 0, stream>>>(z, sx2);
    se2_kernel<<<K_EMB / 256, 256, 0, stream>>>(emb, se2);
    argmin_kernel<<<NPIX / TN, 512, SMEM_BYTES, stream>>>(z, emb, se2, sx2,
                                                          out + OUT_IDX);
    hist_kernel<<<NPIX / 256, 256, 0, stream>>>(out + OUT_IDX, hist);
    quantize_kernel<<<NDTOT / (256 * 4), 256, 0, stream>>>(
        z, emb, out + OUT_IDX, out + OUT_ZQ, sse);
    finalize_kernel<<<1, 256, 0, stream>>>(hist, sse, out);
}